// Round 1
// baseline (1051.781 us; speedup 1.0000x reference)
//
#include <hip/hip_runtime.h>

// GRUModel: B=4096, H=512, V=512, T=31, D_IN=14
// d_out = [probs: 4096*31*512 f32][hidden: 4096*31*512 f32]

#define NB 4096
#define NH 512
#define NT 31
#define NBT 126976        // 4096*31
#define NTH 15872         // 31*512

typedef __bf16 bf16x8 __attribute__((ext_vector_type(8)));
typedef float  f32x4  __attribute__((ext_vector_type(4)));

__device__ __forceinline__ unsigned short f2bf(float f) {
    unsigned u = __float_as_uint(f);
    u = u + 0x7fffu + ((u >> 16) & 1u);
    return (unsigned short)(u >> 16);
}
__device__ __forceinline__ float sigm(float x)  { return 1.f / (1.f + __expf(-x)); }
__device__ __forceinline__ float tanhf_(float x){ return 2.f / (1.f + __expf(-2.f * x)) - 1.f; }

// LDS tiles are [rows][32] bf16 (64B rows). XOR-swizzle the 16B chunk index by
// (r>>1)&3 so frag reads (16 consecutive rows x 4 k-chunks) are <=2-way aliased.
__device__ __forceinline__ int lds_off(int r, int kb) {
    return r * 64 + ((kb ^ ((r >> 1) & 3)) << 4);
}
__device__ __forceinline__ int4 ldg16(const char* g0, int stride, int kbyte, int c) {
    int r = c >> 2, kb = c & 3;
    return *(const int4*)(g0 + (size_t)r * stride + kbyte + kb * 16);
}
__device__ __forceinline__ void sts16(char* lds, int c, int4 v) {
    int r = c >> 2, kb = c & 3;
    *(int4*)(lds + lds_off(r, kb)) = v;
}
__device__ __forceinline__ bf16x8 ldsfrag(const char* lds, int row, int hi) {
    return *(const bf16x8*)(lds + lds_off(row, hi));
}
// load 8 f32, round to bf16, pack to one 16B chunk
__device__ __forceinline__ int4 ldg16_f32(const float* g0, int stride, int koff, int c) {
    int r = c >> 2, kb = c & 3;
    const float4* p = (const float4*)(g0 + (size_t)r * stride + koff + kb * 8);
    float4 a = p[0], b = p[1];
    union { unsigned short us[8]; int4 v; } u;
    u.us[0]=f2bf(a.x); u.us[1]=f2bf(a.y); u.us[2]=f2bf(a.z); u.us[3]=f2bf(a.w);
    u.us[4]=f2bf(b.x); u.us[5]=f2bf(b.y); u.us[6]=f2bf(b.z); u.us[7]=f2bf(b.w);
    return u.v;
}

// ---------------------------------------------------------------- converts
__global__ void k_f32_to_bf16(const float* __restrict__ in,
                              unsigned short* __restrict__ out, int n4) {
    int i = blockIdx.x * 256 + threadIdx.x;
    if (i < n4) {
        float4 v = ((const float4*)in)[i];
        ushort4 o;
        o.x = f2bf(v.x); o.y = f2bf(v.y); o.z = f2bf(v.z); o.w = f2bf(v.w);
        ((ushort4*)out)[i] = o;
    }
}

// ---------------------------------------------------------------- x = inputs @ W_in.T + b_in  -> bf16
__global__ void k_linear_in(const float* __restrict__ inp,   // [4096,14]
                            const float* __restrict__ W,     // [512,14]
                            const float* __restrict__ bias,  // [512]
                            unsigned short* __restrict__ xb) // [4096,512] bf16
{
    int idx = blockIdx.x * 256 + threadIdx.x;   // b*512 + j
    int b = idx >> 9, j = idx & 511;
    const float* ir = inp + (size_t)b * 14;
    const float* wr = W + (size_t)j * 14;
    float acc = bias[j];
#pragma unroll
    for (int k = 0; k < 14; ++k) acc += ir[k] * wr[k];
    xb[idx] = f2bf(acc);
}

// ---------------------------------------------------------------- gi = x @ W_ih.T + b_ih (f32 out)
// BM=128, BN=64, BK=32, 256 thr = 4 waves (2x2), wave tile 64x32
__global__ __launch_bounds__(256) void k_gemm_gi(
    const unsigned short* __restrict__ A,   // [4096,512] bf16
    const unsigned short* __restrict__ W,   // [1536,512] bf16
    const float* __restrict__ bias,         // [1536]
    float* __restrict__ C)                  // [4096,1536]
{
    __shared__ __align__(16) char lA[128 * 64];
    __shared__ __align__(16) char lB[64 * 64];
    const int tid = threadIdx.x, lane = tid & 63, wid = tid >> 6;
    const int wm = wid >> 1, wn = wid & 1, hi = lane >> 4, c16 = lane & 15;
    const int m0 = blockIdx.x * 128, n0 = blockIdx.y * 64;
    const char* ga = (const char*)(A + (size_t)m0 * 512);
    const char* gb = (const char*)(W + (size_t)n0 * 512);
    f32x4 acc[4][2] = {};
    int4 ra0 = ldg16(ga, 1024, 0, tid);
    int4 ra1 = ldg16(ga, 1024, 0, tid + 256);
    int4 rb0 = ldg16(gb, 1024, 0, tid);
    for (int kt = 0; kt < 16; ++kt) {
        if (kt) __syncthreads();
        sts16(lA, tid, ra0); sts16(lA, tid + 256, ra1); sts16(lB, tid, rb0);
        __syncthreads();
        if (kt < 15) {
            int kb = (kt + 1) * 64;
            ra0 = ldg16(ga, 1024, kb, tid);
            ra1 = ldg16(ga, 1024, kb, tid + 256);
            rb0 = ldg16(gb, 1024, kb, tid);
        }
        bf16x8 af[4];
#pragma unroll
        for (int i = 0; i < 4; ++i) af[i] = ldsfrag(lA, wm * 64 + i * 16 + c16, hi);
#pragma unroll
        for (int j = 0; j < 2; ++j) {
            bf16x8 bfr = ldsfrag(lB, wn * 32 + j * 16 + c16, hi);
#pragma unroll
            for (int i = 0; i < 4; ++i)
                acc[i][j] = __builtin_amdgcn_mfma_f32_16x16x32_bf16(af[i], bfr, acc[i][j], 0, 0, 0);
        }
    }
#pragma unroll
    for (int i = 0; i < 4; ++i) {
        int m = m0 + wm * 64 + i * 16 + hi * 4;
#pragma unroll
        for (int j = 0; j < 2; ++j) {
            int n = n0 + wn * 32 + j * 16 + c16;
            float bj = bias[n];
#pragma unroll
            for (int q = 0; q < 4; ++q)
                C[(size_t)(m + q) * 1536 + n] = acc[i][j][q] + bj;
        }
    }
}

// ---------------------------------------------------------------- fused GRU step
// gh = h@W_hh.T + b_hh for all 3 gates, then gate math, write h_new (f32->d_out hidden, bf16->ping-pong)
// BM=128, BN=64 per gate (grid 32x8), BK=32, 4 waves 2x2, wave 64x32 per gate
__device__ __forceinline__ int4 ldg16B3(const char* gW, int n0, int kbyte, int c) {
    int r = c >> 2, kb = c & 3;                     // r in [0,192): gate = r>>6
    int wrow = ((r >> 6) << 9) + n0 + (r & 63);     // W_hh row
    return *(const int4*)(gW + (size_t)wrow * 1024 + kbyte + kb * 16);
}

__global__ __launch_bounds__(256) void k_step(
    const unsigned short* __restrict__ Hin,   // [4096,512] bf16 (t-1 state, unused if t==0)
    const unsigned short* __restrict__ Whh,   // [1536,512] bf16
    const float* __restrict__ gi,             // [4096,1536]
    const float* __restrict__ bhh,            // [1536]
    float* __restrict__ hidden,               // [4096, 15872] f32 (d_out region)
    unsigned short* __restrict__ Hout,        // [4096,512] bf16
    int t)
{
    __shared__ __align__(16) char lA[128 * 64];
    __shared__ __align__(16) char lB[192 * 64];
    const int tid = threadIdx.x, lane = tid & 63, wid = tid >> 6;
    const int wm = wid >> 1, wn = wid & 1, hi = lane >> 4, c16 = lane & 15;
    const int m0 = blockIdx.x * 128, n0 = blockIdx.y * 64;
    f32x4 acc[3][4][2] = {};
    if (t > 0) {
        const char* ga = (const char*)(Hin + (size_t)m0 * 512);
        const char* gw = (const char*)Whh;
        int4 ra0 = ldg16(ga, 1024, 0, tid);
        int4 ra1 = ldg16(ga, 1024, 0, tid + 256);
        int4 rb0 = ldg16B3(gw, n0, 0, tid);
        int4 rb1 = ldg16B3(gw, n0, 0, tid + 256);
        int4 rb2 = ldg16B3(gw, n0, 0, tid + 512);
        for (int kt = 0; kt < 16; ++kt) {
            if (kt) __syncthreads();
            sts16(lA, tid, ra0); sts16(lA, tid + 256, ra1);
            sts16(lB, tid, rb0); sts16(lB, tid + 256, rb1); sts16(lB, tid + 512, rb2);
            __syncthreads();
            if (kt < 15) {
                int kb = (kt + 1) * 64;
                ra0 = ldg16(ga, 1024, kb, tid);
                ra1 = ldg16(ga, 1024, kb, tid + 256);
                rb0 = ldg16B3(gw, n0, kb, tid);
                rb1 = ldg16B3(gw, n0, kb, tid + 256);
                rb2 = ldg16B3(gw, n0, kb, tid + 512);
            }
            bf16x8 af[4];
#pragma unroll
            for (int i = 0; i < 4; ++i) af[i] = ldsfrag(lA, wm * 64 + i * 16 + c16, hi);
#pragma unroll
            for (int g = 0; g < 3; ++g) {
#pragma unroll
                for (int j = 0; j < 2; ++j) {
                    bf16x8 bfr = ldsfrag(lB, g * 64 + wn * 32 + j * 16 + c16, hi);
#pragma unroll
                    for (int i = 0; i < 4; ++i)
                        acc[g][i][j] = __builtin_amdgcn_mfma_f32_16x16x32_bf16(af[i], bfr, acc[g][i][j], 0, 0, 0);
                }
            }
        }
    }
    // epilogue: gate math
#pragma unroll
    for (int i = 0; i < 4; ++i) {
        int mB = m0 + wm * 64 + i * 16 + hi * 4;
#pragma unroll
        for (int j = 0; j < 2; ++j) {
            int n = n0 + wn * 32 + j * 16 + c16;   // gate-local column 0..511
            float br = bhh[n], bz = bhh[512 + n], bn = bhh[1024 + n];
#pragma unroll
            for (int q = 0; q < 4; ++q) {
                int m = mB + q;
                size_t gb0 = (size_t)m * 1536 + n;
                float pr = gi[gb0]        + acc[0][i][j][q] + br;
                float pz = gi[gb0 + 512]  + acc[1][i][j][q] + bz;
                float r  = sigm(pr);
                float z  = sigm(pz);
                float nn = tanhf_(gi[gb0 + 1024] + r * (acc[2][i][j][q] + bn));
                float hold = (t > 0) ? hidden[(size_t)m * NTH + (size_t)(t - 1) * 512 + n] : 0.f;
                float hn = (1.f - z) * nn + z * hold;
                hidden[(size_t)m * NTH + (size_t)t * 512 + n] = hn;
                Hout[(size_t)m * 512 + n] = f2bf(hn);
            }
        }
    }
}

// ---------------------------------------------------------------- projection + softmax
// BM=64, BN=512 (full V), BK=32, 4 waves; wave w owns rows [w*16, w*16+16) x all 512 cols
__global__ __launch_bounds__(256) void k_proj(
    const float* __restrict__ hs,           // [126976,512] f32 (d_out hidden region)
    const unsigned short* __restrict__ Wo,  // [512,512] bf16
    const float* __restrict__ bo,           // [512]
    float* __restrict__ out)                // [126976,512]
{
    __shared__ __align__(16) char lA[64 * 64];
    __shared__ __align__(16) char lB[512 * 64];
    const int tid = threadIdx.x, lane = tid & 63, wid = tid >> 6;
    const int hi = lane >> 4, c16 = lane & 15;
    const int m0 = blockIdx.x * 64;
    const float* ga = hs + (size_t)m0 * 512;
    const char* gb = (const char*)Wo;
    f32x4 acc[32] = {};
    int4 ra = ldg16_f32(ga, 512, 0, tid);
    int4 rb[8];
#pragma unroll
    for (int s = 0; s < 8; ++s) rb[s] = ldg16(gb, 1024, 0, tid + 256 * s);
    for (int kt = 0; kt < 16; ++kt) {
        if (kt) __syncthreads();
        sts16(lA, tid, ra);
#pragma unroll
        for (int s = 0; s < 8; ++s) sts16(lB, tid + 256 * s, rb[s]);
        __syncthreads();
        if (kt < 15) {
            ra = ldg16_f32(ga, 512, (kt + 1) * 32, tid);
#pragma unroll
            for (int s = 0; s < 8; ++s) rb[s] = ldg16(gb, 1024, (kt + 1) * 64, tid + 256 * s);
        }
        bf16x8 af = ldsfrag(lA, wid * 16 + c16, hi);
#pragma unroll
        for (int j = 0; j < 32; ++j) {
            bf16x8 bfr = ldsfrag(lB, j * 16 + c16, hi);
            acc[j] = __builtin_amdgcn_mfma_f32_16x16x32_bf16(af, bfr, acc[j], 0, 0, 0);
        }
    }
    // + bias
#pragma unroll
    for (int j = 0; j < 32; ++j) {
        float bj = bo[j * 16 + c16];
#pragma unroll
        for (int q = 0; q < 4; ++q) acc[j][q] += bj;
    }
    // softmax per row; row = m0 + wid*16 + hi*4 + q lives in the 16 lanes of this hi-group
#pragma unroll
    for (int q = 0; q < 4; ++q) {
        float mx = -3.0e38f;
#pragma unroll
        for (int j = 0; j < 32; ++j) mx = fmaxf(mx, acc[j][q]);
        mx = fmaxf(mx, __shfl_xor(mx, 1));
        mx = fmaxf(mx, __shfl_xor(mx, 2));
        mx = fmaxf(mx, __shfl_xor(mx, 4));
        mx = fmaxf(mx, __shfl_xor(mx, 8));
        float sm = 0.f;
        float ev[32];
#pragma unroll
        for (int j = 0; j < 32; ++j) { ev[j] = __expf(acc[j][q] - mx); sm += ev[j]; }
        sm += __shfl_xor(sm, 1);
        sm += __shfl_xor(sm, 2);
        sm += __shfl_xor(sm, 4);
        sm += __shfl_xor(sm, 8);
        float inv = 1.f / sm;
        int m = m0 + wid * 16 + hi * 4 + q;
        float* orow = out + (size_t)m * 512 + c16;
#pragma unroll
        for (int j = 0; j < 32; ++j) orow[j * 16] = ev[j] * inv;
    }
}

// ---------------------------------------------------------------- launch
extern "C" void kernel_launch(void* const* d_in, const int* in_sizes, int n_in,
                              void* d_out, int out_size, void* d_ws, size_t ws_size,
                              hipStream_t stream) {
    const float* inputs = (const float*)d_in[0];   // [4096,14]
    const float* W_in   = (const float*)d_in[1];   // [512,14]
    const float* b_in   = (const float*)d_in[2];   // [512]
    const float* W_ih   = (const float*)d_in[3];   // [1536,512]
    const float* b_ih   = (const float*)d_in[4];   // [1536]
    const float* W_hh   = (const float*)d_in[5];   // [1536,512]
    const float* b_hh   = (const float*)d_in[6];   // [1536]
    const float* W_out  = (const float*)d_in[7];   // [512,512]
    const float* b_out  = (const float*)d_in[8];   // [512]

    float* out    = (float*)d_out;                       // probs [126976,512]
    float* hidden = out + (size_t)NBT * 512;             // hidden [126976,512] == [4096, 15872]

    char* ws = (char*)d_ws;
    unsigned short* wih_b  = (unsigned short*)(ws);                 // 1536*512 bf16
    unsigned short* whh_b  = (unsigned short*)(ws + 1572864);
    unsigned short* wout_b = (unsigned short*)(ws + 3145728);
    unsigned short* x_b    = (unsigned short*)(ws + 3670016);       // 4096*512 bf16
    float*          gi     = (float*)(ws + 7864320);                // 4096*1536 f32
    unsigned short* hb0    = (unsigned short*)(ws + 33030144);      // 4096*512 bf16
    unsigned short* hb1    = (unsigned short*)(ws + 37224448);

    k_f32_to_bf16<<<768, 256, 0, stream>>>(W_ih, wih_b, 196608);
    k_f32_to_bf16<<<768, 256, 0, stream>>>(W_hh, whh_b, 196608);
    k_f32_to_bf16<<<256, 256, 0, stream>>>(W_out, wout_b, 65536);
    k_linear_in<<<8192, 256, 0, stream>>>(inputs, W_in, b_in, x_b);
    k_gemm_gi<<<dim3(32, 24), 256, 0, stream>>>(x_b, wih_b, b_ih, gi);

    unsigned short* hb[2] = {hb0, hb1};
    for (int t = 0; t < NT; ++t) {
        k_step<<<dim3(32, 8), 256, 0, stream>>>(hb[t & 1], whh_b, gi, b_hh,
                                                hidden, hb[(t + 1) & 1], t);
    }
    k_proj<<<1984, 256, 0, stream>>>(hidden, wout_b, b_out, out);
}